// Round 1
// baseline (325.284 us; speedup 1.0000x reference)
//
#include <hip/hip_runtime.h>
#include <math.h>

// Problem constants (fixed by setup_inputs)
constexpr int BS = 16;
constexpr int NA = 8400;    // 80^2 + 40^2 + 20^2
constexpr int NC = 80;
constexpr int MG = 128;     // M gt boxes
constexpr int TK = 13;      // TOPK

// Output layout (floats), return order: labels, bboxes, scores, fg_mask, tgt_idx
constexpr int OFF_LBL = 0;
constexpr int OFF_BB  = OFF_LBL + BS * NA;          // 134400
constexpr int OFF_SC  = OFF_BB  + BS * NA * 4;      // 672000
constexpr int OFF_FG  = OFF_SC  + BS * NA * NC;     // 11424000
constexpr int OFF_TG  = OFF_FG  + BS * NA;          // 11558400

__device__ __forceinline__ float ciou_f(float gx, float gy, float gz, float gw,
                                        float px, float py, float pz, float pw) {
    const float eps = 1e-7f;
    float w1 = gz - gx, h1 = gw - gy + eps;
    float w2 = pz - px, h2 = pw - py + eps;
    float iw = fmaxf(fminf(gz, pz) - fmaxf(gx, px), 0.f);
    float ih = fmaxf(fminf(gw, pw) - fmaxf(gy, py), 0.f);
    float inter = iw * ih;
    float uni = w1 * h1 + w2 * h2 - inter + eps;
    float iou = inter / uni;
    float cw = fmaxf(gz, pz) - fminf(gx, px);
    float ch = fmaxf(gw, pw) - fminf(gy, py);
    float c2 = cw * cw + ch * ch + eps;
    float dx = px + pz - gx - gz;
    float dy = py + pw - gy - gw;
    float rho2 = (dx * dx + dy * dy) * 0.25f;
    float dat = atanf(w2 / h2) - atanf(w1 / h1);
    float v = 0.4052847345693511f * dat * dat;   // 4/pi^2
    float alpha = v / (v - iou + (1.f + eps));
    return iou - (rho2 / c2 + v * alpha);
}

__device__ __forceinline__ bool inside_gt(float ax, float ay,
                                          float gx, float gy, float gz, float gw) {
    float d = fminf(fminf(ax - gx, ay - gy), fminf(gz - ax, gw - ay));
    return d > 1e-9f;
}

// K2: one block per (b,m). Build align row in LDS, extract top-13 (lowest-index
// tie-break, identical set to jax.lax.top_k), scatter mask_pos + fg counts.
__global__ __launch_bounds__(256) void k_topk(
    const float* __restrict__ pd_scores, const float* __restrict__ pd_bboxes,
    const float* __restrict__ anc, const int* __restrict__ gt_labels,
    const float* __restrict__ gt_bboxes, const float* __restrict__ mask_gt,
    unsigned char* __restrict__ mask_pos, int* __restrict__ fg_cnt)
{
    __shared__ float salign[NA];
    __shared__ float rval[256];
    __shared__ int   ridx[256];
    __shared__ int   ssel[TK];

    int bm = blockIdx.x;
    if (mask_gt[bm] <= 0.f) return;              // row fully masked out
    int b = bm / MG;
    int tid = threadIdx.x;

    const float4 g = *reinterpret_cast<const float4*>(gt_bboxes + bm * 4);
    const int lbl = gt_labels[bm];
    const float* pbb = pd_bboxes + (size_t)b * NA * 4;
    const float* psc = pd_scores + (size_t)b * NA * NC;

    for (int a = tid; a < NA; a += 256) {
        float ax = anc[2 * a], ay = anc[2 * a + 1];
        float al = 0.f;
        if (inside_gt(ax, ay, g.x, g.y, g.z, g.w)) {
            float4 p = *reinterpret_cast<const float4*>(pbb + a * 4);
            float ov = fmaxf(ciou_f(g.x, g.y, g.z, g.w, p.x, p.y, p.z, p.w), 0.f);
            float sc = psc[(size_t)a * NC + lbl];
            float ov2 = ov * ov;
            al = sc * ov2 * ov2 * ov2;           // score^1 * ov^6
        }
        salign[a] = al;
    }
    __syncthreads();

    for (int k = 0; k < TK; ++k) {
        float bv = -1.f; int bi = NA;
        for (int a = tid; a < NA; a += 256) {
            float v = salign[a];
            if (v > bv) { bv = v; bi = a; }      // ascending scan -> lowest idx on tie
        }
        rval[tid] = bv; ridx[tid] = bi;
        __syncthreads();
        for (int s = 128; s > 0; s >>= 1) {
            if (tid < s) {
                float v2 = rval[tid + s]; int i2 = ridx[tid + s];
                if (v2 > rval[tid] || (v2 == rval[tid] && i2 < ridx[tid])) {
                    rval[tid] = v2; ridx[tid] = i2;
                }
            }
            __syncthreads();
        }
        if (tid == 0) { int s = ridx[0]; ssel[k] = s; salign[s] = -1.f; }
        __syncthreads();
    }

    if (tid < TK) {
        int a = ssel[tid];
        float ax = anc[2 * a], ay = anc[2 * a + 1];
        if (inside_gt(ax, ay, g.x, g.y, g.z, g.w)) {   // mask_topk * mask_in_gts
            mask_pos[(size_t)bm * NA + a] = 1;
            atomicAdd(&fg_cnt[b * NA + a], 1);
        }
    }
}

// K3: per anchor — resolve multi-assignment via argmax over m of masked overlaps
// (first-max tie-break); produce target_gt_idx.
__global__ __launch_bounds__(256) void k_dedup(
    const float* __restrict__ pd_bboxes, const float* __restrict__ anc,
    const float* __restrict__ gt_bboxes, const float* __restrict__ mask_gt,
    unsigned char* __restrict__ mask_pos, const int* __restrict__ fg_cnt,
    int* __restrict__ tgt)
{
    int i = blockIdx.x * blockDim.x + threadIdx.x;
    if (i >= BS * NA) return;
    int b = i / NA, a = i - b * NA;
    int cnt = fg_cnt[i];
    int t = 0;
    size_t base = (size_t)b * MG * NA + a;
    if (cnt == 1) {
        for (int m = 0; m < MG; ++m) {
            if (mask_pos[base + (size_t)m * NA]) { t = m; break; }
        }
    } else if (cnt > 1) {
        float ax = anc[2 * a], ay = anc[2 * a + 1];
        float4 p = *reinterpret_cast<const float4*>(pd_bboxes + (size_t)i * 4);
        float bov = -1.f; int bm_ = 0;
        for (int m = 0; m < MG; ++m) {
            float ov = 0.f;
            int gi = b * MG + m;
            if (mask_gt[gi] > 0.f) {
                float4 g = *reinterpret_cast<const float4*>(gt_bboxes + gi * 4);
                if (inside_gt(ax, ay, g.x, g.y, g.z, g.w))
                    ov = fmaxf(ciou_f(g.x, g.y, g.z, g.w, p.x, p.y, p.z, p.w), 0.f);
            }
            if (ov > bov) { bov = ov; bm_ = m; }  // first max
        }
        for (int m = 0; m < MG; ++m)
            mask_pos[base + (size_t)m * NA] = (m == bm_) ? (unsigned char)1 : (unsigned char)0;
        t = bm_;
    }
    tgt[i] = t;
}

// K4: per (b,m) — pos_am / pos_ov maxes over FINAL mask_pos (masked values).
__global__ __launch_bounds__(256) void k_rowmax(
    const float* __restrict__ pd_scores, const float* __restrict__ pd_bboxes,
    const float* __restrict__ anc, const int* __restrict__ gt_labels,
    const float* __restrict__ gt_bboxes, const float* __restrict__ mask_gt,
    const unsigned char* __restrict__ mask_pos,
    float* __restrict__ pos_am, float* __restrict__ pos_ov)
{
    __shared__ float r1[256], r2[256];
    int bm = blockIdx.x;
    int b = bm / MG;
    int tid = threadIdx.x;
    float am_mx = 0.f, ov_mx = 0.f;
    if (mask_gt[bm] > 0.f) {
        const float4 g = *reinterpret_cast<const float4*>(gt_bboxes + bm * 4);
        const int lbl = gt_labels[bm];
        const float* pbb = pd_bboxes + (size_t)b * NA * 4;
        const float* psc = pd_scores + (size_t)b * NA * NC;
        const unsigned char* row = mask_pos + (size_t)bm * NA;
        for (int a = tid; a < NA; a += 256) {
            if (row[a]) {
                float ax = anc[2 * a], ay = anc[2 * a + 1];
                if (inside_gt(ax, ay, g.x, g.y, g.z, g.w)) {
                    float4 p = *reinterpret_cast<const float4*>(pbb + a * 4);
                    float ov = fmaxf(ciou_f(g.x, g.y, g.z, g.w, p.x, p.y, p.z, p.w), 0.f);
                    float sc = psc[(size_t)a * NC + lbl];
                    float ov2 = ov * ov;
                    float al = sc * ov2 * ov2 * ov2;
                    am_mx = fmaxf(am_mx, al);
                    ov_mx = fmaxf(ov_mx, ov);
                }
            }
        }
    }
    r1[tid] = am_mx; r2[tid] = ov_mx;
    __syncthreads();
    for (int s = 128; s > 0; s >>= 1) {
        if (tid < s) {
            r1[tid] = fmaxf(r1[tid], r1[tid + s]);
            r2[tid] = fmaxf(r2[tid], r2[tid + s]);
        }
        __syncthreads();
    }
    if (tid == 0) { pos_am[bm] = r1[0]; pos_ov[bm] = r2[0]; }
}

// K5a: per anchor — labels, bboxes, fg, tgt outputs + norm into ws.
__global__ __launch_bounds__(256) void k_final_scalar(
    const float* __restrict__ pd_scores, const float* __restrict__ pd_bboxes,
    const float* __restrict__ anc, const int* __restrict__ gt_labels,
    const float* __restrict__ gt_bboxes, const float* __restrict__ mask_gt,
    const int* __restrict__ fg_cnt, const int* __restrict__ tgt,
    const float* __restrict__ pos_am, const float* __restrict__ pos_ov,
    float* __restrict__ out, float* __restrict__ norm_ws)
{
    int i = blockIdx.x * blockDim.x + threadIdx.x;
    if (i >= BS * NA) return;
    int b = i / NA, a = i - b * NA;
    int t = tgt[i];
    bool fg = fg_cnt[i] > 0;
    int gi = b * MG + t;
    float4 g = *reinterpret_cast<const float4*>(gt_bboxes + gi * 4);
    int lraw = gt_labels[gi];
    int lbl = lraw > 0 ? lraw : 0;

    float norm = 0.f;
    if (fg) {
        float al = 0.f;
        if (mask_gt[gi] > 0.f) {
            float ax = anc[2 * a], ay = anc[2 * a + 1];
            if (inside_gt(ax, ay, g.x, g.y, g.z, g.w)) {
                float4 p = *reinterpret_cast<const float4*>(pd_bboxes + (size_t)i * 4);
                float ov = fmaxf(ciou_f(g.x, g.y, g.z, g.w, p.x, p.y, p.z, p.w), 0.f);
                float sc = pd_scores[(size_t)i * NC + lraw];
                float ov2 = ov * ov;
                al = sc * ov2 * ov2 * ov2;
            }
        }
        norm = al * pos_ov[gi] / (pos_am[gi] + 1e-9f);
    }

    out[OFF_LBL + i] = (float)lbl;
    float* ob = out + OFF_BB + (size_t)i * 4;
    ob[0] = g.x; ob[1] = g.y; ob[2] = g.z; ob[3] = g.w;
    out[OFF_FG + i] = fg ? 1.f : 0.f;
    out[OFF_TG + i] = (float)t;
    norm_ws[i] = norm;
}

// K5b: fill target_scores (vectorized float4, coalesced).
__global__ __launch_bounds__(256) void k_scores(
    const int* __restrict__ gt_labels, const int* __restrict__ tgt,
    const int* __restrict__ fg_cnt, const float* __restrict__ norm_ws,
    float* __restrict__ out_scores)
{
    int idx = blockIdx.x * blockDim.x + threadIdx.x;   // over BS*NA*20
    if (idx >= BS * NA * (NC / 4)) return;
    int i = idx / (NC / 4);
    int c0 = (idx - i * (NC / 4)) * 4;
    float4 v = {0.f, 0.f, 0.f, 0.f};
    if (fg_cnt[i] > 0) {
        int b = i / NA;
        int lraw = gt_labels[b * MG + tgt[i]];
        int lbl = lraw > 0 ? lraw : 0;
        if (lbl >= c0 && lbl < c0 + 4) {
            float nv = norm_ws[i];
            if (lbl == c0)     v.x = nv;
            else if (lbl == c0 + 1) v.y = nv;
            else if (lbl == c0 + 2) v.z = nv;
            else               v.w = nv;
        }
    }
    reinterpret_cast<float4*>(out_scores)[idx] = v;
}

extern "C" void kernel_launch(void* const* d_in, const int* in_sizes, int n_in,
                              void* d_out, int out_size, void* d_ws, size_t ws_size,
                              hipStream_t stream) {
    const float* pd_scores = (const float*)d_in[0];
    const float* pd_bboxes = (const float*)d_in[1];
    const float* anc       = (const float*)d_in[2];
    const int*   gt_labels = (const int*)d_in[3];
    const float* gt_bboxes = (const float*)d_in[4];
    const float* mask_gt   = (const float*)d_in[5];
    float* out = (float*)d_out;

    // Workspace carve
    unsigned char* w = (unsigned char*)d_ws;
    unsigned char* mask_pos = w;                              // BS*MG*NA bytes
    size_t off = (size_t)BS * MG * NA;                        // 17,203,200 (4-aligned)
    int*   fg_cnt  = (int*)(w + off);   off += (size_t)BS * NA * 4;
    int*   tgt     = (int*)(w + off);   off += (size_t)BS * NA * 4;
    float* pos_am  = (float*)(w + off); off += (size_t)BS * MG * 4;
    float* pos_ov  = (float*)(w + off); off += (size_t)BS * MG * 4;
    float* norm_ws = (float*)(w + off); off += (size_t)BS * NA * 4;

    hipMemsetAsync(mask_pos, 0, (size_t)BS * MG * NA, stream);
    hipMemsetAsync(fg_cnt, 0, (size_t)BS * NA * 4, stream);

    k_topk<<<BS * MG, 256, 0, stream>>>(pd_scores, pd_bboxes, anc, gt_labels,
                                        gt_bboxes, mask_gt, mask_pos, fg_cnt);

    int nA = BS * NA;
    k_dedup<<<(nA + 255) / 256, 256, 0, stream>>>(pd_bboxes, anc, gt_bboxes,
                                                  mask_gt, mask_pos, fg_cnt, tgt);

    k_rowmax<<<BS * MG, 256, 0, stream>>>(pd_scores, pd_bboxes, anc, gt_labels,
                                          gt_bboxes, mask_gt, mask_pos, pos_am, pos_ov);

    k_final_scalar<<<(nA + 255) / 256, 256, 0, stream>>>(
        pd_scores, pd_bboxes, anc, gt_labels, gt_bboxes, mask_gt,
        fg_cnt, tgt, pos_am, pos_ov, out, norm_ws);

    int nS = BS * NA * (NC / 4);
    k_scores<<<(nS + 255) / 256, 256, 0, stream>>>(gt_labels, tgt, fg_cnt,
                                                   norm_ws, out + OFF_SC);
}

// Round 2
// 200.208 us; speedup vs baseline: 1.6247x; 1.6247x over previous
//
#include <hip/hip_runtime.h>
#include <math.h>

// Problem constants (fixed by setup_inputs)
constexpr int BS = 16;
constexpr int NA = 8400;    // 80^2 + 40^2 + 20^2
constexpr int NC = 80;
constexpr int MG = 128;     // M gt boxes
constexpr int TK = 13;      // TOPK
constexpr int NCAND = 1024; // max inside-anchors per gt box: <=894 (box<200^2)

// Output layout (floats), return order: labels, bboxes, scores, fg_mask, tgt_idx
constexpr int OFF_LBL = 0;
constexpr int OFF_BB  = OFF_LBL + BS * NA;
constexpr int OFF_SC  = OFF_BB  + BS * NA * 4;
constexpr int OFF_FG  = OFF_SC  + BS * NA * NC;
constexpr int OFF_TG  = OFF_FG  + BS * NA;

__device__ __forceinline__ float ciou_f(float gx, float gy, float gz, float gw,
                                        float px, float py, float pz, float pw) {
    const float eps = 1e-7f;
    float w1 = gz - gx, h1 = gw - gy + eps;
    float w2 = pz - px, h2 = pw - py + eps;
    float iw = fmaxf(fminf(gz, pz) - fmaxf(gx, px), 0.f);
    float ih = fmaxf(fminf(gw, pw) - fmaxf(gy, py), 0.f);
    float inter = iw * ih;
    float uni = w1 * h1 + w2 * h2 - inter + eps;
    float iou = inter / uni;
    float cw = fmaxf(gz, pz) - fminf(gx, px);
    float ch = fmaxf(gw, pw) - fminf(gy, py);
    float c2 = cw * cw + ch * ch + eps;
    float dx = px + pz - gx - gz;
    float dy = py + pw - gy - gw;
    float rho2 = (dx * dx + dy * dy) * 0.25f;
    float dat = atanf(w2 / h2) - atanf(w1 / h1);
    float v = 0.4052847345693511f * dat * dat;   // 4/pi^2
    float alpha = v / (v - iou + (1.f + eps));
    return iou - (rho2 / c2 + v * alpha);
}

__device__ __forceinline__ bool inside_gt(float ax, float ay,
                                          float gx, float gy, float gz, float gw) {
    float d = fminf(fminf(ax - gx, ay - gy), fminf(gz - ax, gw - ay));
    return d > 1e-9f;
}

// K1: one block per (b,m). Compact positive-align candidates into LDS, run 13
// argmax rounds (exact jax.lax.top_k set semantics incl. lowest-index ties and
// the npos<13 zero-fill), scatter fg counts + selector row.
__global__ __launch_bounds__(256) void k_topk(
    const float* __restrict__ pd_scores, const float* __restrict__ pd_bboxes,
    const float* __restrict__ anc, const int* __restrict__ gt_labels,
    const float* __restrict__ gt_bboxes, const float* __restrict__ mask_gt,
    int* __restrict__ fg_cnt, int* __restrict__ fg_m)
{
    __shared__ float cv[NCAND];
    __shared__ int   ca[NCAND];
    __shared__ int   s_cnt;
    __shared__ unsigned s_pm;           // "align>0" mask for anchors 0..31
    __shared__ float s_wv[4];
    __shared__ int   s_wk[4];

    int bm = blockIdx.x;
    if (mask_gt[bm] <= 0.f) return;              // masked row contributes nothing
    int b = bm / MG;
    int m = bm - b * MG;
    int tid = threadIdx.x;

    if (tid == 0) { s_cnt = 0; s_pm = 0u; }
    __syncthreads();

    const float4 g = *reinterpret_cast<const float4*>(gt_bboxes + bm * 4);
    const int lbl = gt_labels[bm];
    const float* pbb = pd_bboxes + (size_t)b * NA * 4;
    const float* psc = pd_scores + (size_t)b * NA * NC;

    for (int a = tid; a < NA; a += 256) {
        float ax = anc[2 * a], ay = anc[2 * a + 1];
        float al = 0.f;
        if (inside_gt(ax, ay, g.x, g.y, g.z, g.w)) {
            float4 p = *reinterpret_cast<const float4*>(pbb + a * 4);
            float ov = fmaxf(ciou_f(g.x, g.y, g.z, g.w, p.x, p.y, p.z, p.w), 0.f);
            float sc = psc[(size_t)a * NC + lbl];
            float ov2 = ov * ov;
            al = sc * ov2 * ov2 * ov2;           // score^1 * ov^6 (same assoc as before)
        }
        if (al > 0.f) {
            int p = atomicAdd(&s_cnt, 1);
            if (p < NCAND) { cv[p] = al; ca[p] = a; }
            if (a < 32) atomicOr(&s_pm, 1u << a);
        }
    }
    __syncthreads();

    int npos = min(s_cnt, NCAND);
    int rounds = min(npos, TK);
    int* fgc = fg_cnt + b * NA;
    int* fgm = fg_m + b * NA;

    for (int k = 0; k < rounds; ++k) {
        float bv = -1.f; int bk = 0x7fffffff;
        for (int p = tid; p < npos; p += 256) {
            float v = cv[p];
            int key = (ca[p] << 10) | p;         // anchor idx in high bits: ties -> lowest anchor
            if (v > bv || (v == bv && key < bk)) { bv = v; bk = key; }
        }
        for (int off = 32; off > 0; off >>= 1) {
            float v2 = __shfl_down(bv, off);
            int   k2 = __shfl_down(bk, off);
            if (v2 > bv || (v2 == bv && k2 < bk)) { bv = v2; bk = k2; }
        }
        int wid = tid >> 6;
        if ((tid & 63) == 0) { s_wv[wid] = bv; s_wk[wid] = bk; }
        __syncthreads();
        if (tid == 0) {
            for (int w = 1; w < 4; ++w)
                if (s_wv[w] > bv || (s_wv[w] == bv && s_wk[w] < bk)) { bv = s_wv[w]; bk = s_wk[w]; }
            int slot = bk & (NCAND - 1);
            int a = bk >> 10;
            cv[slot] = -1.f;                     // remove winner
            atomicAdd(&fgc[a], 1);
            fgm[a] = m;                          // unique writer when cnt==1
        }
        __syncthreads();
    }

    // npos < TK: top_k fills with the globally lowest-index zero-valued anchors.
    // Fill indices are provably < 26 (< npos positives + 13 fills).
    if (tid == 0) {
        int need = TK - rounds;
        if (need > 0) {
            unsigned pm = s_pm;
            for (int idx = 0; idx < 32 && need > 0; ++idx) {
                if (!((pm >> idx) & 1u)) {
                    float ax = anc[2 * idx], ay = anc[2 * idx + 1];
                    if (inside_gt(ax, ay, g.x, g.y, g.z, g.w)) {  // mask_in_gts filter
                        atomicAdd(&fgc[idx], 1);
                        fgm[idx] = m;
                    }
                    --need;
                }
            }
        }
    }
}

// K2: per anchor — resolve assignment (cnt==1 direct; cnt>1 argmax over masked
// overlaps, first-max tie-break), write labels/bboxes/fg/tgt outputs, feed
// per-row pos_am/pos_ov via atomicMax (float-as-uint, all values >= 0).
__global__ __launch_bounds__(256) void k_assign(
    const float* __restrict__ pd_scores, const float* __restrict__ pd_bboxes,
    const float* __restrict__ anc, const int* __restrict__ gt_labels,
    const float* __restrict__ gt_bboxes, const float* __restrict__ mask_gt,
    const int* __restrict__ fg_cnt, const int* __restrict__ fg_m,
    float* __restrict__ out, float* __restrict__ am_ws,
    int* __restrict__ gi_ws, int* __restrict__ lbl_ws,
    unsigned* __restrict__ pos_am, unsigned* __restrict__ pos_ov)
{
    int i = blockIdx.x * 256 + threadIdx.x;
    if (i >= BS * NA) return;
    int b = i / NA, a = i - b * NA;
    int cnt = fg_cnt[i];
    int t = 0;
    if (cnt == 1) {
        t = fg_m[i];
    } else if (cnt > 1) {
        float ax = anc[2 * a], ay = anc[2 * a + 1];
        float4 p = *reinterpret_cast<const float4*>(pd_bboxes + (size_t)i * 4);
        float bov = -1.f; int bm_ = 0;
        for (int mm = 0; mm < MG; ++mm) {
            int gi = b * MG + mm;
            float ov = 0.f;
            if (mask_gt[gi] > 0.f) {
                float4 g = *reinterpret_cast<const float4*>(gt_bboxes + gi * 4);
                if (inside_gt(ax, ay, g.x, g.y, g.z, g.w))
                    ov = fmaxf(ciou_f(g.x, g.y, g.z, g.w, p.x, p.y, p.z, p.w), 0.f);
            }
            if (ov > bov) { bov = ov; bm_ = mm; }   // first max
        }
        t = bm_;
    }
    bool fg = cnt > 0;
    int gi = b * MG + t;
    float4 g = *reinterpret_cast<const float4*>(gt_bboxes + gi * 4);
    int lraw = gt_labels[gi];
    int lbl = lraw > 0 ? lraw : 0;

    float am = 0.f, ovv = 0.f;
    if (fg && mask_gt[gi] > 0.f) {
        float ax = anc[2 * a], ay = anc[2 * a + 1];
        if (inside_gt(ax, ay, g.x, g.y, g.z, g.w)) {
            float4 p = *reinterpret_cast<const float4*>(pd_bboxes + (size_t)i * 4);
            float ov = fmaxf(ciou_f(g.x, g.y, g.z, g.w, p.x, p.y, p.z, p.w), 0.f);
            float sc = pd_scores[(size_t)b * NA * NC + (size_t)a * NC + lraw];
            float ov2 = ov * ov;
            am = sc * ov2 * ov2 * ov2;
            ovv = ov;
        }
    }
    if (fg) {
        atomicMax(&pos_am[gi], __float_as_uint(am));
        atomicMax(&pos_ov[gi], __float_as_uint(ovv));
    }

    out[OFF_LBL + i] = (float)lbl;
    float4* ob = reinterpret_cast<float4*>(out + OFF_BB) + i;
    *ob = g;
    out[OFF_FG + i] = fg ? 1.f : 0.f;
    out[OFF_TG + i] = (float)t;
    am_ws[i]  = am;
    gi_ws[i]  = fg ? gi : -1;
    lbl_ws[i] = lbl;
}

// K3: fill target_scores (float4 coalesced; 20 quads per anchor).
__global__ __launch_bounds__(256) void k_scores(
    const float* __restrict__ am_ws, const int* __restrict__ gi_ws,
    const int* __restrict__ lbl_ws,
    const float* __restrict__ pos_am, const float* __restrict__ pos_ov,
    float* __restrict__ out_scores)
{
    int idx = blockIdx.x * 256 + threadIdx.x;   // over BS*NA*(NC/4)
    if (idx >= BS * NA * (NC / 4)) return;
    int i = idx / (NC / 4);
    int q = idx - i * (NC / 4);
    float4 v = {0.f, 0.f, 0.f, 0.f};
    int gi = gi_ws[i];
    if (gi >= 0) {
        int lbl = lbl_ws[i];
        if ((lbl >> 2) == q) {
            float norm = am_ws[i] * pos_ov[gi] / (pos_am[gi] + 1e-9f);
            reinterpret_cast<float*>(&v)[lbl & 3] = norm;
        }
    }
    reinterpret_cast<float4*>(out_scores)[idx] = v;
}

extern "C" void kernel_launch(void* const* d_in, const int* in_sizes, int n_in,
                              void* d_out, int out_size, void* d_ws, size_t ws_size,
                              hipStream_t stream) {
    const float* pd_scores = (const float*)d_in[0];
    const float* pd_bboxes = (const float*)d_in[1];
    const float* anc       = (const float*)d_in[2];
    const int*   gt_labels = (const int*)d_in[3];
    const float* gt_bboxes = (const float*)d_in[4];
    const float* mask_gt   = (const float*)d_in[5];
    float* out = (float*)d_out;

    // Workspace carve (zero-init region first: fg_cnt + pos_am + pos_ov)
    unsigned char* w = (unsigned char*)d_ws;
    size_t off = 0;
    int*      fg_cnt = (int*)(w + off);      off += (size_t)BS * NA * 4;
    unsigned* pos_am = (unsigned*)(w + off); off += (size_t)BS * MG * 4;
    unsigned* pos_ov = (unsigned*)(w + off); off += (size_t)BS * MG * 4;
    size_t zero_bytes = off;
    int*      fg_m   = (int*)(w + off);      off += (size_t)BS * NA * 4;
    float*    am_ws  = (float*)(w + off);    off += (size_t)BS * NA * 4;
    int*      gi_ws  = (int*)(w + off);      off += (size_t)BS * NA * 4;
    int*      lbl_ws = (int*)(w + off);      off += (size_t)BS * NA * 4;

    hipMemsetAsync(w, 0, zero_bytes, stream);

    k_topk<<<BS * MG, 256, 0, stream>>>(pd_scores, pd_bboxes, anc, gt_labels,
                                        gt_bboxes, mask_gt, fg_cnt, fg_m);

    int nA = BS * NA;
    k_assign<<<(nA + 255) / 256, 256, 0, stream>>>(
        pd_scores, pd_bboxes, anc, gt_labels, gt_bboxes, mask_gt,
        fg_cnt, fg_m, out, am_ws, gi_ws, lbl_ws, pos_am, pos_ov);

    int nS = BS * NA * (NC / 4);
    k_scores<<<(nS + 255) / 256, 256, 0, stream>>>(
        am_ws, gi_ws, lbl_ws, (const float*)pos_am, (const float*)pos_ov,
        out + OFF_SC);
}